// Round 6
// baseline (231.929 us; speedup 1.0000x reference)
//
#include <hip/hip_runtime.h>
#include <math.h>

#define BB 128
#define QQ 900
#define GG 80
#define CC 92
#define NCL 91
#define NSLOT 15  // ceil(QQ/64)

#define NPART 8   // front: parts per batch
#define QPB 128   // q rows per front block

// ---------------- ws layout (bytes) ---------------- (UNCHANGED)
#define COST_OFF 0            // float[BB*GG*QQ]  36,864,000
#define LSE_OFF  36864000     // float[BB*QQ]
#define VIDX_OFF 37324800     // int[BB*GG]
#define NV_OFF   37365760     // int[BB]
#define FPART_OFF 37366272    // float[BB*NPART=1024] CE-base partials
#define MPART_OFF 37370368    // double[BB*3] lsa matched partials [ce,l1,giou]

#define FRONT_LDS_BYTES (QPB * 93 * 4)   // 47,616 -> 3 blocks/CU

// Fused front kernel (r1 form, verbatim): grid BB*8, 128 thr, 128 q each,
// padded-93 LDS layout, bit-identical fp32 expression trees.
__global__ __launch_bounds__(128) void front_kernel(const float* __restrict__ logits,
                                                    const float* __restrict__ pboxes,
                                                    const float* __restrict__ gboxes,
                                                    const int* __restrict__ glabels,
                                                    float* __restrict__ lse_g,
                                                    int* __restrict__ valid_idx,
                                                    int* __restrict__ nvalid,
                                                    float* __restrict__ cost,
                                                    float* __restrict__ fpart) {
    extern __shared__ float sL[];  // [QPB][93]
    __shared__ int svidx[GG];
    __shared__ int s_n;
    __shared__ int slab[GG];
    __shared__ float sgx0[GG], sgy0[GG], sgx1[GG], sgy1[GG], sgar[GG];
    __shared__ float sgcx[GG], sgcy[GG], sgcz[GG], sgcw[GG];
    __shared__ double sce[2];
    int blk = blockIdx.x;
    int b = blk >> 3;
    int part = blk & 7;
    int tid = threadIdx.x;
    int q0 = part * QPB;
    int qcnt = QQ - q0;
    if (qcnt > QPB) qcnt = QPB;
    if (tid < 64) {
        int lane = tid;
        bool v0 = glabels[b * GG + lane] < NCL;
        bool v1 = (lane < GG - 64) ? (glabels[b * GG + 64 + lane] < NCL) : false;
        unsigned long long m0 = __ballot(v0);
        unsigned long long m1 = __ballot(v1);
        int c0 = __popcll(m0);
        unsigned long long lower = lane ? (~0ULL >> (64 - lane)) : 0ULL;
        if (v0) { int p = __popcll(m0 & lower); svidx[p] = lane; valid_idx[b * GG + p] = lane; }
        if (v1) { int p = c0 + __popcll(m1 & lower); svidx[p] = 64 + lane; valid_idx[b * GG + p] = 64 + lane; }
        if (lane == 0) { s_n = c0 + __popcll(m1); nvalid[b] = s_n; }
    }
    __syncthreads();
    int n = s_n;

    // stage logits slab -> LDS (coalesced dword reads; padded stride 93)
    {
        const float* src = logits + ((size_t)b * QQ + q0) * CC;
        for (int i = tid; i < qcnt * CC; i += 128) {
            int ql = i / CC;
            int c = i - ql * CC;
            sL[ql * 93 + c] = src[i];
        }
    }
    // gt staging
    for (int k = tid; k < n; k += 128) {
        int g = svidx[k];
        slab[k] = glabels[b * GG + g];
        float4 gb = ((const float4*)gboxes)[b * GG + g];
        sgcx[k] = gb.x; sgcy[k] = gb.y; sgcz[k] = gb.z; sgcw[k] = gb.w;
        float gx0 = gb.x - 0.5f * gb.z, gy0 = gb.y - 0.5f * gb.w;
        float gx1 = gb.x + 0.5f * gb.z, gy1 = gb.y + 0.5f * gb.w;
        sgx0[k] = gx0; sgy0[k] = gy0; sgx1[k] = gx1; sgy1[k] = gy1;
        sgar[k] = (gx1 - gx0) * (gy1 - gy0);
    }
    __syncthreads();

    int q = q0 + tid;
    bool qok = tid < qcnt;
    const float* row = sL + tid * 93;

    // lse (identical expression tree; values from LDS are identical)
    double local = 0.0;
    float lse_q = 0.f;
    if (qok) {
        float mx = -INFINITY;
        for (int c = 0; c < 23; ++c) {
            float x0 = row[4 * c], x1 = row[4 * c + 1], x2 = row[4 * c + 2], x3 = row[4 * c + 3];
            mx = fmaxf(mx, fmaxf(fmaxf(x0, x1), fmaxf(x2, x3)));
        }
        float ssum = 0.f;
        float e91 = 0.f;
        for (int c = 0; c < 23; ++c) {
            float x0 = row[4 * c], x1 = row[4 * c + 1], x2 = row[4 * c + 2], x3 = row[4 * c + 3];
            ssum += expf(x0 - mx) + expf(x1 - mx) + expf(x2 - mx) + expf(x3 - mx);
            if (c == 22) e91 = x3;  // element 91
        }
        lse_q = mx + logf(ssum);
        lse_g[b * QQ + q] = lse_q;
        local = (double)lse_q - (double)e91;
    }
#pragma unroll
    for (int off = 32; off; off >>= 1) local += __shfl_down(local, off);
    if ((tid & 63) == 0) sce[tid >> 6] = local;

    // cost (identical fp32 op order; gather from LDS)
    if (qok) {
        float4 pb = ((const float4*)pboxes)[b * QQ + q];
        float px0 = pb.x - 0.5f * pb.z, py0 = pb.y - 0.5f * pb.w;
        float px1 = pb.x + 0.5f * pb.z, py1 = pb.y + 0.5f * pb.w;
        float parea = (px1 - px0) * (py1 - py0);
        for (int k = 0; k < n; ++k) {
            float l1 = fabsf(pb.x - sgcx[k]) + fabsf(pb.y - sgcy[k]) +
                       fabsf(pb.z - sgcz[k]) + fabsf(pb.w - sgcw[k]);
            float ltx = fmaxf(px0, sgx0[k]), lty = fmaxf(py0, sgy0[k]);
            float rbx = fminf(px1, sgx1[k]), rby = fminf(py1, sgy1[k]);
            float iw = fmaxf(rbx - ltx, 0.f), ih = fmaxf(rby - lty, 0.f);
            float inter = iw * ih;
            float uni = parea + sgar[k] - inter;
            float iou = inter / uni;
            float cx0 = fminf(px0, sgx0[k]), cy0 = fminf(py0, sgy0[k]);
            float cx1 = fmaxf(px1, sgx1[k]), cy1 = fmaxf(py1, sgy1[k]);
            float cw = fmaxf(cx1 - cx0, 0.f), ch = fmaxf(cy1 - cy0, 0.f);
            float ac = cw * ch;
            float giou = iou - (ac - uni) / ac;
            float cls = lse_q - row[slab[k]];
            cost[((size_t)(b * GG + k)) * QQ + q] = 5.f * l1 + cls - 2.f * giou;
        }
    }
    __syncthreads();
    if (tid == 0) fpart[blk] = (float)(sce[0] + sce[1]);
}

// Wave64 u64 min-reduce via double-DPP (row_shr 1/2/4/8 + bcast15/31), valid in
// lane 63, broadcast via readlane.
__device__ __forceinline__ unsigned long long wave_min_u64(unsigned long long x) {
#define KSTEP(ctrl)                                                                              \
    {                                                                                            \
        unsigned lo = (unsigned)x, hi = (unsigned)(x >> 32);                                     \
        unsigned lo_t = (unsigned)__builtin_amdgcn_update_dpp((int)lo, (int)lo, ctrl, 0xF, 0xF,  \
                                                              false);                            \
        unsigned hi_t = (unsigned)__builtin_amdgcn_update_dpp((int)hi, (int)hi, ctrl, 0xF, 0xF,  \
                                                              false);                            \
        unsigned long long t = ((unsigned long long)hi_t << 32) | lo_t;                          \
        x = t < x ? t : x;                                                                       \
    }
    KSTEP(0x111) KSTEP(0x112) KSTEP(0x114) KSTEP(0x118) KSTEP(0x142) KSTEP(0x143)
#undef KSTEP
    unsigned lo = (unsigned)__builtin_amdgcn_readlane((int)(unsigned)x, 63);
    unsigned hi = (unsigned)__builtin_amdgcn_readlane((int)(unsigned)(x >> 32), 63);
    return ((unsigned long long)hi << 32) | lo;
}

// One exact SAP phase (scipy semantics) for row `cur`.
// R10-proven dataflow + fused u64 min+argmin (r5) + NEW 2-deep prefetch:
// pop 0 consumes pf (row cur, issued TWO phases ago -> a full ~phase of
// latency cover instead of ~300cy); at phase end pf is refilled with row
// cur+2. Same addresses, same bits (cost is immutable during lsa) ->
// traversal identical. Caller alternates two fixed register buffers.
__device__ __forceinline__ bool sap_phase(int cur, int lane, const float* cbase,
                                          unsigned valid_mask, float (&v)[NSLOT],
                                          int (&r4c_r)[NSLOT], float (&u_r)[2],
                                          int (&c4r_r)[2], float (&pf)[NSLOT], int nrows) {
    float sh[NSLOT];
    int path_r[NSLOT];
    float srv_r[2] = {0.f, 0.f};
    unsigned sc = 0, srm = 0;
#pragma unroll
    for (int s = 0; s < NSLOT; ++s) sh[s] = INFINITY;
    int i2 = cur;
    float minv = 0.f;
    int sink = -1;
    for (int pop = 0; pop < QQ && sink < 0; ++pop) {
        float cv[NSLOT];
        if (pop == 0) {
#pragma unroll
            for (int s = 0; s < NSLOT; ++s) cv[s] = pf[s];
        } else {
            const float* crow = cbase + (size_t)i2 * QQ;
#pragma unroll
            for (int s = 0; s < NSLOT; ++s) {
                int j = s * 64 + lane;
                cv[s] = (j < QQ) ? crow[j] : 0.f;
            }
        }
        float uv = (i2 >> 6) ? u_r[1] : u_r[0];
        float ui = __uint_as_float(
            (unsigned)__builtin_amdgcn_readlane((int)__float_as_uint(uv), i2 & 63));
        float base = minv - ui;
        unsigned act = valid_mask & ~sc;
        // per-slot keys + sh update (sh/path updates identical to reference)
        unsigned long long kk[16];
#pragma unroll
        for (int s = 0; s < NSLOT; ++s) {
            bool a = (act >> s) & 1u;
            float r = base + cv[s] - v[s];
            if (a && r < sh[s]) { sh[s] = r; path_r[s] = i2; }
            unsigned u = __float_as_uint(sh[s]);
            u ^= ((int)u < 0) ? 0xFFFFFFFFu : 0x80000000u;
            kk[s] = a ? (((unsigned long long)u << 32) | (unsigned)(s * 64 + lane)) : ~0ULL;
        }
        kk[15] = ~0ULL;
#pragma unroll
        for (int d = 8; d; d >>= 1)
#pragma unroll
            for (int s = 0; s < d; ++s) kk[s] = kk[s] < kk[s + d] ? kk[s] : kk[s + d];
        unsigned long long g = wave_min_u64(kk[0]);
        int lj = (int)(unsigned)g;  // lowest column among ties
        unsigned mu = (unsigned)(g >> 32);
        minv = __uint_as_float((mu & 0x80000000u) ? (mu ^ 0x80000000u) : ~mu);
        if (lane == (lj & 63)) sc |= (1u << (lj >> 6));
        int rv = -1;
#pragma unroll
        for (int s = 0; s < NSLOT; ++s)
            if (s == (lj >> 6)) rv = r4c_r[s];
        int r4c = __builtin_amdgcn_readlane(rv, lj & 63);
        if (r4c == -1) {
            sink = lj;
        } else {
            i2 = r4c;
            if (lane == (i2 & 63)) {
#pragma unroll
                for (int s = 0; s < 2; ++s)
                    if (s == (i2 >> 6)) { srm |= (1u << s); srv_r[s] = minv; }
            }
        }
    }
    if (sink < 0) return false;
    // refill this buffer with row cur+2 (consumed two phases from now) --
    // flies under the dual-update + augment chain AND all of the next phase
    {
        int nxt = cur + 2;
        if (nxt < nrows) {
            const float* nrow = cbase + (size_t)nxt * QQ;
#pragma unroll
            for (int s = 0; s < NSLOT; ++s) {
                int j = s * 64 + lane;
                pf[s] = (j < QQ) ? nrow[j] : 0.f;
            }
        }
    }
    // dual updates (reference order: before augmentation)
    if (lane == (cur & 63)) {
#pragma unroll
        for (int s = 0; s < 2; ++s)
            if (s == (cur >> 6)) u_r[s] += minv;
    }
#pragma unroll
    for (int s = 0; s < 2; ++s)
        if ((srm >> s) & 1u) u_r[s] += minv - srv_r[s];
#pragma unroll
    for (int s = 0; s < NSLOT; ++s)
        if ((sc >> s) & 1u) v[s] -= (minv - sh[s]);
    // augment (wave-cooperative, uniform walk)
    int j = sink;
    while (true) {
        int pslot = j >> 6, plane = j & 63;
        int pv = 0;
#pragma unroll
        for (int s = 0; s < NSLOT; ++s)
            if (s == pslot) pv = path_r[s];
        int pi = __builtin_amdgcn_readlane(pv, plane);
        if (lane == plane) {
#pragma unroll
            for (int s = 0; s < NSLOT; ++s)
                if (s == pslot) r4c_r[s] = pi;
        }
        int cslot = pi >> 6, clane = pi & 63;
        int cvv = 0;
#pragma unroll
        for (int s = 0; s < 2; ++s)
            if (s == cslot) cvv = c4r_r[s];
        int nj = __builtin_amdgcn_readlane(cvv, clane);
        if (lane == clane) {
#pragma unroll
            for (int s = 0; s < 2; ++s)
                if (s == cslot) c4r_r[s] = j;
        }
        j = nj;
        if (pi == cur) break;
    }
    return true;
}

// R10-proven exact LSA: v=0 init, sequential SAP rows 0..n-1 (scipy traversal).
// One 64-lane wave per batch, all state in registers. + 2-deep alternating
// prefetch (pfA/pfB) + fused u64 min+argmin reduction.
__global__ __launch_bounds__(64, 1) void lsa_kernel(const float* __restrict__ cost,
                                                    const int* __restrict__ nvalid,
                                                    const int* __restrict__ valid_idx,
                                                    const int* __restrict__ glabels,
                                                    const float* __restrict__ lse_g,
                                                    const float* __restrict__ pboxes,
                                                    const float* __restrict__ gboxes,
                                                    const float* __restrict__ logits,
                                                    double* __restrict__ mpart) {
    int b = blockIdx.x;
    int n = nvalid[b];
    const float* cbase = cost + (size_t)b * GG * QQ;
    int lane = threadIdx.x;

    float v[NSLOT];
    int r4c_r[NSLOT];
    float u_r[2];
    int c4r_r[2];
    float pfA[NSLOT], pfB[NSLOT];
    unsigned valid_mask = 0x3FFFu | ((lane < QQ - 14 * 64) ? 0x4000u : 0u);
#pragma unroll
    for (int s = 0; s < NSLOT; ++s) { v[s] = 0.f; r4c_r[s] = -1; pfA[s] = 0.f; pfB[s] = 0.f; }
#pragma unroll
    for (int s = 0; s < 2; ++s) { u_r[s] = 0.f; c4r_r[s] = -1; }

    if (n > 0) {  // prime pfA with row 0
#pragma unroll
        for (int s = 0; s < NSLOT; ++s) {
            int j = s * 64 + lane;
            pfA[s] = (j < QQ) ? cbase[j] : 0.f;
        }
    }
    if (n > 1) {  // prime pfB with row 1
        const float* r1 = cbase + QQ;
#pragma unroll
        for (int s = 0; s < NSLOT; ++s) {
            int j = s * 64 + lane;
            pfB[s] = (j < QQ) ? r1[j] : 0.f;
        }
    }
    {
        int cur = 0;
        for (; cur + 1 < n; cur += 2) {
            sap_phase(cur, lane, cbase, valid_mask, v, r4c_r, u_r, c4r_r, pfA, n);
            sap_phase(cur + 1, lane, cbase, valid_mask, v, r4c_r, u_r, c4r_r, pfB, n);
        }
        if (cur < n)
            sap_phase(cur, lane, cbase, valid_mask, v, r4c_r, u_r, c4r_r, pfA, n);
    }

    // ---- fused matched-pair losses ----
    double ce = 0.0, dl1 = 0.0, dgi = 0.0;
#pragma unroll
    for (int s = 0; s < 2; ++s) {
        int r = s * 64 + lane;
        int q = c4r_r[s];
        if (r < n && q >= 0 && q < QQ) {
            int g = valid_idx[b * GG + r];
            int label = glabels[b * GG + g];
            if (label < 0 || label >= CC) label = 0;
            size_t ro = ((size_t)b * QQ + q) * CC;
            float ls = lse_g[b * QQ + q];
            float nll_lab = ls - logits[ro + label];
            float nll_no = ls - logits[ro + NCL];
            ce += 0.1 * (double)nll_lab - (double)nll_no;
            float4 pb = ((const float4*)pboxes)[b * QQ + q];
            float4 gb = ((const float4*)gboxes)[b * GG + g];
            float l1 = fabsf(pb.x - gb.x) + fabsf(pb.y - gb.y) + fabsf(pb.z - gb.z) + fabsf(pb.w - gb.w);
            float px0 = pb.x - 0.5f * pb.z, py0 = pb.y - 0.5f * pb.w;
            float px1 = pb.x + 0.5f * pb.z, py1 = pb.y + 0.5f * pb.w;
            float gx0 = gb.x - 0.5f * gb.z, gy0 = gb.y - 0.5f * gb.w;
            float gx1 = gb.x + 0.5f * gb.z, gy1 = gb.y + 0.5f * gb.w;
            float parea = (px1 - px0) * (py1 - py0);
            float garea = (gx1 - gx0) * (gy1 - gy0);
            float ltx = fmaxf(px0, gx0), lty = fmaxf(py0, gy0);
            float rbx = fminf(px1, gx1), rby = fminf(py1, gy1);
            float iw = fmaxf(rbx - ltx, 0.f), ih = fmaxf(rby - lty, 0.f);
            float inter = iw * ih;
            float uni = parea + garea - inter;
            float iou = inter / uni;
            float cx0 = fminf(px0, gx0), cy0 = fminf(py0, gy0);
            float cx1 = fmaxf(px1, gx1), cy1 = fmaxf(py1, gy1);
            float cw = fmaxf(cx1 - cx0, 0.f), ch = fmaxf(cy1 - cy0, 0.f);
            float ac = cw * ch;
            float giou = iou - (ac - uni) / ac;
            dl1 += (double)l1;
            dgi += 1.0 - (double)giou;
        }
    }
#pragma unroll
    for (int off = 32; off; off >>= 1) {
        ce += __shfl_down(ce, off);
        dl1 += __shfl_down(dl1, off);
        dgi += __shfl_down(dgi, off);
    }
    if (lane == 0) {
        mpart[b * 3 + 0] = ce;
        mpart[b * 3 + 1] = dl1;
        mpart[b * 3 + 2] = dgi;
    }
}

// One wave: sum partials + nvalid -> the three losses (no atomics anywhere).
__global__ __launch_bounds__(64) void final_kernel(const int* __restrict__ nvalid,
                                                   const float* __restrict__ fpart,
                                                   const double* __restrict__ mpart,
                                                   float* __restrict__ out) {
    int lane = threadIdx.x;
    int m = nvalid[lane] + nvalid[64 + lane];  // BB = 128
    double fb = 0.0;
    for (int i = lane; i < BB * NPART; i += 64) fb += (double)fpart[i];
    double ce = 0.0, dl1 = 0.0, dgi = 0.0;
#pragma unroll
    for (int s = 0; s < 2; ++s) {
        int bb = s * 64 + lane;
        ce += mpart[bb * 3 + 0];
        dl1 += mpart[bb * 3 + 1];
        dgi += mpart[bb * 3 + 2];
    }
#pragma unroll
    for (int off = 32; off; off >>= 1) {
        m += __shfl_down(m, off);
        fb += __shfl_down(fb, off);
        ce += __shfl_down(ce, off);
        dl1 += __shfl_down(dl1, off);
        dgi += __shfl_down(dgi, off);
    }
    if (lane == 0) {
        double M = (double)m;
        double sum_w = (double)(BB * QQ) - 0.9 * M;
        out[0] = (float)((fb + ce) / sum_w);
        out[1] = (float)(dl1 / (4.0 * M));
        out[2] = (float)(dgi / M);
    }
}

extern "C" void kernel_launch(void* const* d_in, const int* in_sizes, int n_in,
                              void* d_out, int out_size, void* d_ws, size_t ws_size,
                              hipStream_t stream) {
    const float* logits = (const float*)d_in[0];
    const float* pboxes = (const float*)d_in[1];
    const int* glabels = (const int*)d_in[2];
    const float* gboxes = (const float*)d_in[3];
    float* out = (float*)d_out;

    char* ws = (char*)d_ws;
    float* cost = (float*)(ws + COST_OFF);
    float* lse = (float*)(ws + LSE_OFF);
    int* vidx = (int*)(ws + VIDX_OFF);
    int* nval = (int*)(ws + NV_OFF);
    float* fpart = (float*)(ws + FPART_OFF);
    double* mpart = (double*)(ws + MPART_OFF);

    (void)hipFuncSetAttribute((const void*)front_kernel,
                              hipFuncAttributeMaxDynamicSharedMemorySize, FRONT_LDS_BYTES);

    front_kernel<<<BB * NPART, 128, FRONT_LDS_BYTES, stream>>>(logits, pboxes, gboxes, glabels,
                                                               lse, vidx, nval, cost, fpart);
    lsa_kernel<<<BB, 64, 0, stream>>>(cost, nval, vidx, glabels, lse, pboxes, gboxes, logits, mpart);
    final_kernel<<<1, 64, 0, stream>>>(nval, fpart, mpart, out);
}

// Round 7
// 223.741 us; speedup vs baseline: 1.0366x; 1.0366x over previous
//
#include <hip/hip_runtime.h>
#include <math.h>

#define BB 128
#define QQ 900
#define GG 80
#define CC 92
#define NCL 91
#define NSLOT 15  // ceil(QQ/64)

#define NPART 8   // front: parts per batch
#define QPB 128   // q rows per front block

// ---------------- ws layout (bytes) ---------------- (UNCHANGED)
#define COST_OFF 0            // float[BB*GG*QQ]  36,864,000
#define LSE_OFF  36864000     // float[BB*QQ]
#define VIDX_OFF 37324800     // int[BB*GG]
#define NV_OFF   37365760     // int[BB]
#define FPART_OFF 37366272    // float[BB*NPART=1024] CE-base partials
#define MPART_OFF 37370368    // double[BB*3] lsa matched partials [ce,l1,giou]

#define FRONT_LDS_BYTES (QPB * 93 * 4)   // 47,616 -> 3 blocks/CU

// Fused front kernel (r1 form, verbatim): grid BB*8, 128 thr, 128 q each,
// padded-93 LDS layout, bit-identical fp32 expression trees.
__global__ __launch_bounds__(128) void front_kernel(const float* __restrict__ logits,
                                                    const float* __restrict__ pboxes,
                                                    const float* __restrict__ gboxes,
                                                    const int* __restrict__ glabels,
                                                    float* __restrict__ lse_g,
                                                    int* __restrict__ valid_idx,
                                                    int* __restrict__ nvalid,
                                                    float* __restrict__ cost,
                                                    float* __restrict__ fpart) {
    extern __shared__ float sL[];  // [QPB][93]
    __shared__ int svidx[GG];
    __shared__ int s_n;
    __shared__ int slab[GG];
    __shared__ float sgx0[GG], sgy0[GG], sgx1[GG], sgy1[GG], sgar[GG];
    __shared__ float sgcx[GG], sgcy[GG], sgcz[GG], sgcw[GG];
    __shared__ double sce[2];
    int blk = blockIdx.x;
    int b = blk >> 3;
    int part = blk & 7;
    int tid = threadIdx.x;
    int q0 = part * QPB;
    int qcnt = QQ - q0;
    if (qcnt > QPB) qcnt = QPB;
    if (tid < 64) {
        int lane = tid;
        bool v0 = glabels[b * GG + lane] < NCL;
        bool v1 = (lane < GG - 64) ? (glabels[b * GG + 64 + lane] < NCL) : false;
        unsigned long long m0 = __ballot(v0);
        unsigned long long m1 = __ballot(v1);
        int c0 = __popcll(m0);
        unsigned long long lower = lane ? (~0ULL >> (64 - lane)) : 0ULL;
        if (v0) { int p = __popcll(m0 & lower); svidx[p] = lane; valid_idx[b * GG + p] = lane; }
        if (v1) { int p = c0 + __popcll(m1 & lower); svidx[p] = 64 + lane; valid_idx[b * GG + p] = 64 + lane; }
        if (lane == 0) { s_n = c0 + __popcll(m1); nvalid[b] = s_n; }
    }
    __syncthreads();
    int n = s_n;

    // stage logits slab -> LDS (coalesced dword reads; padded stride 93)
    {
        const float* src = logits + ((size_t)b * QQ + q0) * CC;
        for (int i = tid; i < qcnt * CC; i += 128) {
            int ql = i / CC;
            int c = i - ql * CC;
            sL[ql * 93 + c] = src[i];
        }
    }
    // gt staging
    for (int k = tid; k < n; k += 128) {
        int g = svidx[k];
        slab[k] = glabels[b * GG + g];
        float4 gb = ((const float4*)gboxes)[b * GG + g];
        sgcx[k] = gb.x; sgcy[k] = gb.y; sgcz[k] = gb.z; sgcw[k] = gb.w;
        float gx0 = gb.x - 0.5f * gb.z, gy0 = gb.y - 0.5f * gb.w;
        float gx1 = gb.x + 0.5f * gb.z, gy1 = gb.y + 0.5f * gb.w;
        sgx0[k] = gx0; sgy0[k] = gy0; sgx1[k] = gx1; sgy1[k] = gy1;
        sgar[k] = (gx1 - gx0) * (gy1 - gy0);
    }
    __syncthreads();

    int q = q0 + tid;
    bool qok = tid < qcnt;
    const float* row = sL + tid * 93;

    // lse (identical expression tree; values from LDS are identical)
    double local = 0.0;
    float lse_q = 0.f;
    if (qok) {
        float mx = -INFINITY;
        for (int c = 0; c < 23; ++c) {
            float x0 = row[4 * c], x1 = row[4 * c + 1], x2 = row[4 * c + 2], x3 = row[4 * c + 3];
            mx = fmaxf(mx, fmaxf(fmaxf(x0, x1), fmaxf(x2, x3)));
        }
        float ssum = 0.f;
        float e91 = 0.f;
        for (int c = 0; c < 23; ++c) {
            float x0 = row[4 * c], x1 = row[4 * c + 1], x2 = row[4 * c + 2], x3 = row[4 * c + 3];
            ssum += expf(x0 - mx) + expf(x1 - mx) + expf(x2 - mx) + expf(x3 - mx);
            if (c == 22) e91 = x3;  // element 91
        }
        lse_q = mx + logf(ssum);
        lse_g[b * QQ + q] = lse_q;
        local = (double)lse_q - (double)e91;
    }
#pragma unroll
    for (int off = 32; off; off >>= 1) local += __shfl_down(local, off);
    if ((tid & 63) == 0) sce[tid >> 6] = local;

    // cost (identical fp32 op order; gather from LDS)
    if (qok) {
        float4 pb = ((const float4*)pboxes)[b * QQ + q];
        float px0 = pb.x - 0.5f * pb.z, py0 = pb.y - 0.5f * pb.w;
        float px1 = pb.x + 0.5f * pb.z, py1 = pb.y + 0.5f * pb.w;
        float parea = (px1 - px0) * (py1 - py0);
        for (int k = 0; k < n; ++k) {
            float l1 = fabsf(pb.x - sgcx[k]) + fabsf(pb.y - sgcy[k]) +
                       fabsf(pb.z - sgcz[k]) + fabsf(pb.w - sgcw[k]);
            float ltx = fmaxf(px0, sgx0[k]), lty = fmaxf(py0, sgy0[k]);
            float rbx = fminf(px1, sgx1[k]), rby = fminf(py1, sgy1[k]);
            float iw = fmaxf(rbx - ltx, 0.f), ih = fmaxf(rby - lty, 0.f);
            float inter = iw * ih;
            float uni = parea + sgar[k] - inter;
            float iou = inter / uni;
            float cx0 = fminf(px0, sgx0[k]), cy0 = fminf(py0, sgy0[k]);
            float cx1 = fmaxf(px1, sgx1[k]), cy1 = fmaxf(py1, sgy1[k]);
            float cw = fmaxf(cx1 - cx0, 0.f), ch = fmaxf(cy1 - cy0, 0.f);
            float ac = cw * ch;
            float giou = iou - (ac - uni) / ac;
            float cls = lse_q - row[slab[k]];
            cost[((size_t)(b * GG + k)) * QQ + q] = 5.f * l1 + cls - 2.f * giou;
        }
    }
    __syncthreads();
    if (tid == 0) fpart[blk] = (float)(sce[0] + sce[1]);
}

// Wave64 u64 min-reduce via double-DPP (row_shr 1/2/4/8 + bcast15/31), valid in
// lane 63, broadcast via readlane.
__device__ __forceinline__ unsigned long long wave_min_u64(unsigned long long x) {
#define KSTEP(ctrl)                                                                              \
    {                                                                                            \
        unsigned lo = (unsigned)x, hi = (unsigned)(x >> 32);                                     \
        unsigned lo_t = (unsigned)__builtin_amdgcn_update_dpp((int)lo, (int)lo, ctrl, 0xF, 0xF,  \
                                                              false);                            \
        unsigned hi_t = (unsigned)__builtin_amdgcn_update_dpp((int)hi, (int)hi, ctrl, 0xF, 0xF,  \
                                                              false);                            \
        unsigned long long t = ((unsigned long long)hi_t << 32) | lo_t;                          \
        x = t < x ? t : x;                                                                       \
    }
    KSTEP(0x111) KSTEP(0x112) KSTEP(0x114) KSTEP(0x118) KSTEP(0x142) KSTEP(0x143)
#undef KSTEP
    unsigned lo = (unsigned)__builtin_amdgcn_readlane((int)(unsigned)x, 63);
    unsigned hi = (unsigned)__builtin_amdgcn_readlane((int)(unsigned)(x >> 32), 63);
    return ((unsigned long long)hi << 32) | lo;
}

// One exact SAP phase (scipy semantics) for row `cur`.
// R10-proven dataflow + 2-deep prefetch (r6) + NEW lean scan: r0's cheap f32
// lmin/lslot scan (8 instr/slot, integrated with the sh update) feeding ONE
// 64-bit key (ord(lmin)<<32 | lslot*64+lane) and ONE u64 wave reduction.
// Tie-break identical to the r0 two-reduction scheme: within-lane strict <
// keeps the lowest tied slot (= lowest column, since col = s*64+lane grows
// with s); across lanes equal ord => equal lmin => u64 min picks the lowest
// column among gmin lanes. minv recovered bit-exactly (ord is a bijection;
// values never NaN). This removes r5's ~12-instr/slot key build + 15-u64 tree
// (~200cy/pop) that made r5 a wash.
__device__ __forceinline__ bool sap_phase(int cur, int lane, const float* cbase,
                                          unsigned valid_mask, float (&v)[NSLOT],
                                          int (&r4c_r)[NSLOT], float (&u_r)[2],
                                          int (&c4r_r)[2], float (&pf)[NSLOT], int nrows) {
    float sh[NSLOT];
    int path_r[NSLOT];
    float srv_r[2] = {0.f, 0.f};
    unsigned sc = 0, srm = 0;
#pragma unroll
    for (int s = 0; s < NSLOT; ++s) sh[s] = INFINITY;
    int i2 = cur;
    float minv = 0.f;
    int sink = -1;
    for (int pop = 0; pop < QQ && sink < 0; ++pop) {
        float cv[NSLOT];
        if (pop == 0) {
#pragma unroll
            for (int s = 0; s < NSLOT; ++s) cv[s] = pf[s];
        } else {
            const float* crow = cbase + (size_t)i2 * QQ;
#pragma unroll
            for (int s = 0; s < NSLOT; ++s) {
                int j = s * 64 + lane;
                cv[s] = (j < QQ) ? crow[j] : 0.f;
            }
        }
        float uv = (i2 >> 6) ? u_r[1] : u_r[0];
        float ui = __uint_as_float(
            (unsigned)__builtin_amdgcn_readlane((int)__float_as_uint(uv), i2 & 63));
        float base = minv - ui;
        unsigned act = valid_mask & ~sc;
        float lmin = INFINITY;
        int lslot = 0;
#pragma unroll
        for (int s = 0; s < NSLOT; ++s) {
            if ((act >> s) & 1u) {
                float r = base + cv[s] - v[s];
                if (r < sh[s]) { sh[s] = r; path_r[s] = i2; }
                if (sh[s] < lmin) { lmin = sh[s]; lslot = s; }
            }
        }
        unsigned u = __float_as_uint(lmin);
        u ^= ((int)u < 0) ? 0xFFFFFFFFu : 0x80000000u;
        unsigned long long key =
            ((unsigned long long)u << 32) | (unsigned)(lslot * 64 + lane);
        unsigned long long g = wave_min_u64(key);
        int lj = (int)(unsigned)g;  // lowest column among ties
        unsigned mu = (unsigned)(g >> 32);
        minv = __uint_as_float((mu & 0x80000000u) ? (mu ^ 0x80000000u) : ~mu);
        if (lane == (lj & 63)) sc |= (1u << (lj >> 6));
        int rv = -1;
#pragma unroll
        for (int s = 0; s < NSLOT; ++s)
            if (s == (lj >> 6)) rv = r4c_r[s];
        int r4c = __builtin_amdgcn_readlane(rv, lj & 63);
        if (r4c == -1) {
            sink = lj;
        } else {
            i2 = r4c;
            if (lane == (i2 & 63)) {
#pragma unroll
                for (int s = 0; s < 2; ++s)
                    if (s == (i2 >> 6)) { srm |= (1u << s); srv_r[s] = minv; }
            }
        }
    }
    if (sink < 0) return false;
    // refill this buffer with row cur+2 (consumed two phases from now) --
    // flies under the dual-update + augment chain AND all of the next phase
    {
        int nxt = cur + 2;
        if (nxt < nrows) {
            const float* nrow = cbase + (size_t)nxt * QQ;
#pragma unroll
            for (int s = 0; s < NSLOT; ++s) {
                int j = s * 64 + lane;
                pf[s] = (j < QQ) ? nrow[j] : 0.f;
            }
        }
    }
    // dual updates (reference order: before augmentation)
    if (lane == (cur & 63)) {
#pragma unroll
        for (int s = 0; s < 2; ++s)
            if (s == (cur >> 6)) u_r[s] += minv;
    }
#pragma unroll
    for (int s = 0; s < 2; ++s)
        if ((srm >> s) & 1u) u_r[s] += minv - srv_r[s];
#pragma unroll
    for (int s = 0; s < NSLOT; ++s)
        if ((sc >> s) & 1u) v[s] -= (minv - sh[s]);
    // augment (wave-cooperative, uniform walk)
    int j = sink;
    while (true) {
        int pslot = j >> 6, plane = j & 63;
        int pv = 0;
#pragma unroll
        for (int s = 0; s < NSLOT; ++s)
            if (s == pslot) pv = path_r[s];
        int pi = __builtin_amdgcn_readlane(pv, plane);
        if (lane == plane) {
#pragma unroll
            for (int s = 0; s < NSLOT; ++s)
                if (s == pslot) r4c_r[s] = pi;
        }
        int cslot = pi >> 6, clane = pi & 63;
        int cvv = 0;
#pragma unroll
        for (int s = 0; s < 2; ++s)
            if (s == cslot) cvv = c4r_r[s];
        int nj = __builtin_amdgcn_readlane(cvv, clane);
        if (lane == clane) {
#pragma unroll
            for (int s = 0; s < 2; ++s)
                if (s == cslot) c4r_r[s] = j;
        }
        j = nj;
        if (pi == cur) break;
    }
    return true;
}

// R10-proven exact LSA: v=0 init, sequential SAP rows 0..n-1 (scipy traversal).
// One 64-lane wave per batch, all state in registers. + 2-deep alternating
// prefetch (pfA/pfB) + lean-scan fused u64 min+argmin reduction.
__global__ __launch_bounds__(64, 1) void lsa_kernel(const float* __restrict__ cost,
                                                    const int* __restrict__ nvalid,
                                                    const int* __restrict__ valid_idx,
                                                    const int* __restrict__ glabels,
                                                    const float* __restrict__ lse_g,
                                                    const float* __restrict__ pboxes,
                                                    const float* __restrict__ gboxes,
                                                    const float* __restrict__ logits,
                                                    double* __restrict__ mpart) {
    int b = blockIdx.x;
    int n = nvalid[b];
    const float* cbase = cost + (size_t)b * GG * QQ;
    int lane = threadIdx.x;

    float v[NSLOT];
    int r4c_r[NSLOT];
    float u_r[2];
    int c4r_r[2];
    float pfA[NSLOT], pfB[NSLOT];
    unsigned valid_mask = 0x3FFFu | ((lane < QQ - 14 * 64) ? 0x4000u : 0u);
#pragma unroll
    for (int s = 0; s < NSLOT; ++s) { v[s] = 0.f; r4c_r[s] = -1; pfA[s] = 0.f; pfB[s] = 0.f; }
#pragma unroll
    for (int s = 0; s < 2; ++s) { u_r[s] = 0.f; c4r_r[s] = -1; }

    if (n > 0) {  // prime pfA with row 0
#pragma unroll
        for (int s = 0; s < NSLOT; ++s) {
            int j = s * 64 + lane;
            pfA[s] = (j < QQ) ? cbase[j] : 0.f;
        }
    }
    if (n > 1) {  // prime pfB with row 1
        const float* r1 = cbase + QQ;
#pragma unroll
        for (int s = 0; s < NSLOT; ++s) {
            int j = s * 64 + lane;
            pfB[s] = (j < QQ) ? r1[j] : 0.f;
        }
    }
    {
        int cur = 0;
        for (; cur + 1 < n; cur += 2) {
            sap_phase(cur, lane, cbase, valid_mask, v, r4c_r, u_r, c4r_r, pfA, n);
            sap_phase(cur + 1, lane, cbase, valid_mask, v, r4c_r, u_r, c4r_r, pfB, n);
        }
        if (cur < n)
            sap_phase(cur, lane, cbase, valid_mask, v, r4c_r, u_r, c4r_r, pfA, n);
    }

    // ---- fused matched-pair losses ----
    double ce = 0.0, dl1 = 0.0, dgi = 0.0;
#pragma unroll
    for (int s = 0; s < 2; ++s) {
        int r = s * 64 + lane;
        int q = c4r_r[s];
        if (r < n && q >= 0 && q < QQ) {
            int g = valid_idx[b * GG + r];
            int label = glabels[b * GG + g];
            if (label < 0 || label >= CC) label = 0;
            size_t ro = ((size_t)b * QQ + q) * CC;
            float ls = lse_g[b * QQ + q];
            float nll_lab = ls - logits[ro + label];
            float nll_no = ls - logits[ro + NCL];
            ce += 0.1 * (double)nll_lab - (double)nll_no;
            float4 pb = ((const float4*)pboxes)[b * QQ + q];
            float4 gb = ((const float4*)gboxes)[b * GG + g];
            float l1 = fabsf(pb.x - gb.x) + fabsf(pb.y - gb.y) + fabsf(pb.z - gb.z) + fabsf(pb.w - gb.w);
            float px0 = pb.x - 0.5f * pb.z, py0 = pb.y - 0.5f * pb.w;
            float px1 = pb.x + 0.5f * pb.z, py1 = pb.y + 0.5f * pb.w;
            float gx0 = gb.x - 0.5f * gb.z, gy0 = gb.y - 0.5f * gb.w;
            float gx1 = gb.x + 0.5f * gb.z, gy1 = gb.y + 0.5f * gb.w;
            float parea = (px1 - px0) * (py1 - py0);
            float garea = (gx1 - gx0) * (gy1 - gy0);
            float ltx = fmaxf(px0, gx0), lty = fmaxf(py0, gy0);
            float rbx = fminf(px1, gx1), rby = fminf(py1, gy1);
            float iw = fmaxf(rbx - ltx, 0.f), ih = fmaxf(rby - lty, 0.f);
            float inter = iw * ih;
            float uni = parea + garea - inter;
            float iou = inter / uni;
            float cx0 = fminf(px0, gx0), cy0 = fminf(py0, gy0);
            float cx1 = fmaxf(px1, gx1), cy1 = fmaxf(py1, gy1);
            float cw = fmaxf(cx1 - cx0, 0.f), ch = fmaxf(cy1 - cy0, 0.f);
            float ac = cw * ch;
            float giou = iou - (ac - uni) / ac;
            dl1 += (double)l1;
            dgi += 1.0 - (double)giou;
        }
    }
#pragma unroll
    for (int off = 32; off; off >>= 1) {
        ce += __shfl_down(ce, off);
        dl1 += __shfl_down(dl1, off);
        dgi += __shfl_down(dgi, off);
    }
    if (lane == 0) {
        mpart[b * 3 + 0] = ce;
        mpart[b * 3 + 1] = dl1;
        mpart[b * 3 + 2] = dgi;
    }
}

// One wave: sum partials + nvalid -> the three losses (no atomics anywhere).
__global__ __launch_bounds__(64) void final_kernel(const int* __restrict__ nvalid,
                                                   const float* __restrict__ fpart,
                                                   const double* __restrict__ mpart,
                                                   float* __restrict__ out) {
    int lane = threadIdx.x;
    int m = nvalid[lane] + nvalid[64 + lane];  // BB = 128
    double fb = 0.0;
    for (int i = lane; i < BB * NPART; i += 64) fb += (double)fpart[i];
    double ce = 0.0, dl1 = 0.0, dgi = 0.0;
#pragma unroll
    for (int s = 0; s < 2; ++s) {
        int bb = s * 64 + lane;
        ce += mpart[bb * 3 + 0];
        dl1 += mpart[bb * 3 + 1];
        dgi += mpart[bb * 3 + 2];
    }
#pragma unroll
    for (int off = 32; off; off >>= 1) {
        m += __shfl_down(m, off);
        fb += __shfl_down(fb, off);
        ce += __shfl_down(ce, off);
        dl1 += __shfl_down(dl1, off);
        dgi += __shfl_down(dgi, off);
    }
    if (lane == 0) {
        double M = (double)m;
        double sum_w = (double)(BB * QQ) - 0.9 * M;
        out[0] = (float)((fb + ce) / sum_w);
        out[1] = (float)(dl1 / (4.0 * M));
        out[2] = (float)(dgi / M);
    }
}

extern "C" void kernel_launch(void* const* d_in, const int* in_sizes, int n_in,
                              void* d_out, int out_size, void* d_ws, size_t ws_size,
                              hipStream_t stream) {
    const float* logits = (const float*)d_in[0];
    const float* pboxes = (const float*)d_in[1];
    const int* glabels = (const int*)d_in[2];
    const float* gboxes = (const float*)d_in[3];
    float* out = (float*)d_out;

    char* ws = (char*)d_ws;
    float* cost = (float*)(ws + COST_OFF);
    float* lse = (float*)(ws + LSE_OFF);
    int* vidx = (int*)(ws + VIDX_OFF);
    int* nval = (int*)(ws + NV_OFF);
    float* fpart = (float*)(ws + FPART_OFF);
    double* mpart = (double*)(ws + MPART_OFF);

    (void)hipFuncSetAttribute((const void*)front_kernel,
                              hipFuncAttributeMaxDynamicSharedMemorySize, FRONT_LDS_BYTES);

    front_kernel<<<BB * NPART, 128, FRONT_LDS_BYTES, stream>>>(logits, pboxes, gboxes, glabels,
                                                               lse, vidx, nval, cost, fpart);
    lsa_kernel<<<BB, 64, 0, stream>>>(cost, nval, vidx, glabels, lse, pboxes, gboxes, logits, mpart);
    final_kernel<<<1, 64, 0, stream>>>(nval, fpart, mpart, out);
}

// Round 8
// 213.392 us; speedup vs baseline: 1.0869x; 1.0485x over previous
//
#include <hip/hip_runtime.h>
#include <math.h>

#define BB 128
#define QQ 900
#define GG 80
#define CC 92
#define NCL 91
#define NSLOT 16  // 4 groups x 4 elems; col j = (s>>2)*256 + lane*4 + (s&3)

#define NPART 8   // front: parts per batch
#define QPB 128   // q rows per front block

// ---------------- ws layout (bytes) ---------------- (UNCHANGED)
#define COST_OFF 0            // float[BB*GG*QQ]  36,864,000
#define LSE_OFF  36864000     // float[BB*QQ]
#define VIDX_OFF 37324800     // int[BB*GG]
#define NV_OFF   37365760     // int[BB]
#define FPART_OFF 37366272    // float[BB*NPART=1024] CE-base partials
#define MPART_OFF 37370368    // double[BB*3] lsa matched partials [ce,l1,giou]

#define FRONT_LDS_BYTES (QPB * 93 * 4)   // 47,616 -> 3 blocks/CU

// Fused front kernel (r1 form, verbatim): grid BB*8, 128 thr, 128 q each,
// padded-93 LDS layout, bit-identical fp32 expression trees.
__global__ __launch_bounds__(128) void front_kernel(const float* __restrict__ logits,
                                                    const float* __restrict__ pboxes,
                                                    const float* __restrict__ gboxes,
                                                    const int* __restrict__ glabels,
                                                    float* __restrict__ lse_g,
                                                    int* __restrict__ valid_idx,
                                                    int* __restrict__ nvalid,
                                                    float* __restrict__ cost,
                                                    float* __restrict__ fpart) {
    extern __shared__ float sL[];  // [QPB][93]
    __shared__ int svidx[GG];
    __shared__ int s_n;
    __shared__ int slab[GG];
    __shared__ float sgx0[GG], sgy0[GG], sgx1[GG], sgy1[GG], sgar[GG];
    __shared__ float sgcx[GG], sgcy[GG], sgcz[GG], sgcw[GG];
    __shared__ double sce[2];
    int blk = blockIdx.x;
    int b = blk >> 3;
    int part = blk & 7;
    int tid = threadIdx.x;
    int q0 = part * QPB;
    int qcnt = QQ - q0;
    if (qcnt > QPB) qcnt = QPB;
    if (tid < 64) {
        int lane = tid;
        bool v0 = glabels[b * GG + lane] < NCL;
        bool v1 = (lane < GG - 64) ? (glabels[b * GG + 64 + lane] < NCL) : false;
        unsigned long long m0 = __ballot(v0);
        unsigned long long m1 = __ballot(v1);
        int c0 = __popcll(m0);
        unsigned long long lower = lane ? (~0ULL >> (64 - lane)) : 0ULL;
        if (v0) { int p = __popcll(m0 & lower); svidx[p] = lane; valid_idx[b * GG + p] = lane; }
        if (v1) { int p = c0 + __popcll(m1 & lower); svidx[p] = 64 + lane; valid_idx[b * GG + p] = 64 + lane; }
        if (lane == 0) { s_n = c0 + __popcll(m1); nvalid[b] = s_n; }
    }
    __syncthreads();
    int n = s_n;

    // stage logits slab -> LDS (coalesced dword reads; padded stride 93)
    {
        const float* src = logits + ((size_t)b * QQ + q0) * CC;
        for (int i = tid; i < qcnt * CC; i += 128) {
            int ql = i / CC;
            int c = i - ql * CC;
            sL[ql * 93 + c] = src[i];
        }
    }
    // gt staging
    for (int k = tid; k < n; k += 128) {
        int g = svidx[k];
        slab[k] = glabels[b * GG + g];
        float4 gb = ((const float4*)gboxes)[b * GG + g];
        sgcx[k] = gb.x; sgcy[k] = gb.y; sgcz[k] = gb.z; sgcw[k] = gb.w;
        float gx0 = gb.x - 0.5f * gb.z, gy0 = gb.y - 0.5f * gb.w;
        float gx1 = gb.x + 0.5f * gb.z, gy1 = gb.y + 0.5f * gb.w;
        sgx0[k] = gx0; sgy0[k] = gy0; sgx1[k] = gx1; sgy1[k] = gy1;
        sgar[k] = (gx1 - gx0) * (gy1 - gy0);
    }
    __syncthreads();

    int q = q0 + tid;
    bool qok = tid < qcnt;
    const float* row = sL + tid * 93;

    // lse (identical expression tree; values from LDS are identical)
    double local = 0.0;
    float lse_q = 0.f;
    if (qok) {
        float mx = -INFINITY;
        for (int c = 0; c < 23; ++c) {
            float x0 = row[4 * c], x1 = row[4 * c + 1], x2 = row[4 * c + 2], x3 = row[4 * c + 3];
            mx = fmaxf(mx, fmaxf(fmaxf(x0, x1), fmaxf(x2, x3)));
        }
        float ssum = 0.f;
        float e91 = 0.f;
        for (int c = 0; c < 23; ++c) {
            float x0 = row[4 * c], x1 = row[4 * c + 1], x2 = row[4 * c + 2], x3 = row[4 * c + 3];
            ssum += expf(x0 - mx) + expf(x1 - mx) + expf(x2 - mx) + expf(x3 - mx);
            if (c == 22) e91 = x3;  // element 91
        }
        lse_q = mx + logf(ssum);
        lse_g[b * QQ + q] = lse_q;
        local = (double)lse_q - (double)e91;
    }
#pragma unroll
    for (int off = 32; off; off >>= 1) local += __shfl_down(local, off);
    if ((tid & 63) == 0) sce[tid >> 6] = local;

    // cost (identical fp32 op order; gather from LDS)
    if (qok) {
        float4 pb = ((const float4*)pboxes)[b * QQ + q];
        float px0 = pb.x - 0.5f * pb.z, py0 = pb.y - 0.5f * pb.w;
        float px1 = pb.x + 0.5f * pb.z, py1 = pb.y + 0.5f * pb.w;
        float parea = (px1 - px0) * (py1 - py0);
        for (int k = 0; k < n; ++k) {
            float l1 = fabsf(pb.x - sgcx[k]) + fabsf(pb.y - sgcy[k]) +
                       fabsf(pb.z - sgcz[k]) + fabsf(pb.w - sgcw[k]);
            float ltx = fmaxf(px0, sgx0[k]), lty = fmaxf(py0, sgy0[k]);
            float rbx = fminf(px1, sgx1[k]), rby = fminf(py1, sgy1[k]);
            float iw = fmaxf(rbx - ltx, 0.f), ih = fmaxf(rby - lty, 0.f);
            float inter = iw * ih;
            float uni = parea + sgar[k] - inter;
            float iou = inter / uni;
            float cx0 = fminf(px0, sgx0[k]), cy0 = fminf(py0, sgy0[k]);
            float cx1 = fmaxf(px1, sgx1[k]), cy1 = fmaxf(py1, sgy1[k]);
            float cw = fmaxf(cx1 - cx0, 0.f), ch = fmaxf(cy1 - cy0, 0.f);
            float ac = cw * ch;
            float giou = iou - (ac - uni) / ac;
            float cls = lse_q - row[slab[k]];
            cost[((size_t)(b * GG + k)) * QQ + q] = 5.f * l1 + cls - 2.f * giou;
        }
    }
    __syncthreads();
    if (tid == 0) fpart[blk] = (float)(sce[0] + sce[1]);
}

// Wave64 u64 min-reduce via double-DPP (row_shr 1/2/4/8 + bcast15/31), valid in
// lane 63, broadcast via readlane.
__device__ __forceinline__ unsigned long long wave_min_u64(unsigned long long x) {
#define KSTEP(ctrl)                                                                              \
    {                                                                                            \
        unsigned lo = (unsigned)x, hi = (unsigned)(x >> 32);                                     \
        unsigned lo_t = (unsigned)__builtin_amdgcn_update_dpp((int)lo, (int)lo, ctrl, 0xF, 0xF,  \
                                                              false);                            \
        unsigned hi_t = (unsigned)__builtin_amdgcn_update_dpp((int)hi, (int)hi, ctrl, 0xF, 0xF,  \
                                                              false);                            \
        unsigned long long t = ((unsigned long long)hi_t << 32) | lo_t;                          \
        x = t < x ? t : x;                                                                       \
    }
    KSTEP(0x111) KSTEP(0x112) KSTEP(0x114) KSTEP(0x118) KSTEP(0x142) KSTEP(0x143)
#undef KSTEP
    unsigned lo = (unsigned)__builtin_amdgcn_readlane((int)(unsigned)x, 63);
    unsigned hi = (unsigned)__builtin_amdgcn_readlane((int)(unsigned)(x >> 32), 63);
    return ((unsigned long long)hi << 32) | lo;
}

// Column mapping helpers for the float4 layout:
//   slot s (0..15): group g=s>>2, elem e=s&3; column j = g*256 + lane*4 + e.
//   For fixed lane, j is strictly increasing in s, so the within-lane scan's
//   strict-< tie keeps the lowest column; the u64 key carries the ACTUAL
//   column, so the global tie-break (lowest column among minima) is computed
//   over the identical (value, column) set as the reference => same traversal.
#define COL_OWNER_LANE(j) (((j) & 255) >> 2)
#define COL_SLOT(j) (((((j) >> 8)) << 2) | ((j) & 3))

// Load one cost row into cv[16] with the float4 mapping. Groups 0..2 cover
// columns 0..767 for all lanes; group 3 covers 768..899 (lanes 0..32 only).
__device__ __forceinline__ void load_row_f4(const float* crow, int lane, float (&cv)[NSLOT]) {
    const float4* c4 = (const float4*)crow;  // row stride 3600B, 16B-aligned
    float4 a0 = c4[lane];
    float4 a1 = c4[64 + lane];
    float4 a2 = c4[128 + lane];
    float4 a3 = make_float4(0.f, 0.f, 0.f, 0.f);
    if (lane <= 32) a3 = c4[192 + lane];
    cv[0] = a0.x; cv[1] = a0.y; cv[2] = a0.z; cv[3] = a0.w;
    cv[4] = a1.x; cv[5] = a1.y; cv[6] = a1.z; cv[7] = a1.w;
    cv[8] = a2.x; cv[9] = a2.y; cv[10] = a2.z; cv[11] = a2.w;
    cv[12] = a3.x; cv[13] = a3.y; cv[14] = a3.z; cv[15] = a3.w;
}

// One exact SAP phase (scipy semantics) for row `cur`.
// R10-proven dataflow + 2-deep prefetch (r6) + lean-scan u64 reduce (r7) +
// NEW float4 column remap: 4 global_load_dwordx4 per pop instead of 15
// scalar dword loads (same bytes, same values, fewer issue slots + addr
// chains). Per-column arithmetic and tie-break semantics bit-identical (see
// mapping note above).
__device__ __forceinline__ bool sap_phase(int cur, int lane, const float* cbase,
                                          unsigned valid_mask, float (&v)[NSLOT],
                                          int (&r4c_r)[NSLOT], float (&u_r)[2],
                                          int (&c4r_r)[2], float (&pf)[NSLOT], int nrows) {
    float sh[NSLOT];
    int path_r[NSLOT];
    float srv_r[2] = {0.f, 0.f};
    unsigned sc = 0, srm = 0;
#pragma unroll
    for (int s = 0; s < NSLOT; ++s) sh[s] = INFINITY;
    int i2 = cur;
    float minv = 0.f;
    int sink = -1;
    for (int pop = 0; pop < QQ && sink < 0; ++pop) {
        float cv[NSLOT];
        if (pop == 0) {
#pragma unroll
            for (int s = 0; s < NSLOT; ++s) cv[s] = pf[s];
        } else {
            load_row_f4(cbase + (size_t)i2 * QQ, lane, cv);
        }
        float uv = (i2 >> 6) ? u_r[1] : u_r[0];
        float ui = __uint_as_float(
            (unsigned)__builtin_amdgcn_readlane((int)__float_as_uint(uv), i2 & 63));
        float base = minv - ui;
        unsigned act = valid_mask & ~sc;
        float lmin = INFINITY;
        int lslot = 0;
#pragma unroll
        for (int s = 0; s < NSLOT; ++s) {
            if ((act >> s) & 1u) {
                float r = base + cv[s] - v[s];
                if (r < sh[s]) { sh[s] = r; path_r[s] = i2; }
                if (sh[s] < lmin) { lmin = sh[s]; lslot = s; }
            }
        }
        int jcol = ((lslot >> 2) << 8) + lane * 4 + (lslot & 3);  // actual column
        unsigned u = __float_as_uint(lmin);
        u ^= ((int)u < 0) ? 0xFFFFFFFFu : 0x80000000u;
        unsigned long long key = ((unsigned long long)u << 32) | (unsigned)jcol;
        unsigned long long g = wave_min_u64(key);
        int lj = (int)(unsigned)g;  // lowest column among ties
        unsigned mu = (unsigned)(g >> 32);
        minv = __uint_as_float((mu & 0x80000000u) ? (mu ^ 0x80000000u) : ~mu);
        int ol = COL_OWNER_LANE(lj);
        int os = COL_SLOT(lj);
        if (lane == ol) sc |= (1u << os);
        int rv = -1;
#pragma unroll
        for (int s = 0; s < NSLOT; ++s)
            if (s == os) rv = r4c_r[s];
        int r4c = __builtin_amdgcn_readlane(rv, ol);
        if (r4c == -1) {
            sink = lj;
        } else {
            i2 = r4c;
            if (lane == (i2 & 63)) {
#pragma unroll
                for (int s = 0; s < 2; ++s)
                    if (s == (i2 >> 6)) { srm |= (1u << s); srv_r[s] = minv; }
            }
        }
    }
    if (sink < 0) return false;
    // refill this buffer with row cur+2 (consumed two phases from now) --
    // flies under the dual-update + augment chain AND all of the next phase
    {
        int nxt = cur + 2;
        if (nxt < nrows) load_row_f4(cbase + (size_t)nxt * QQ, lane, pf);
    }
    // dual updates (reference order: before augmentation)
    if (lane == (cur & 63)) {
#pragma unroll
        for (int s = 0; s < 2; ++s)
            if (s == (cur >> 6)) u_r[s] += minv;
    }
#pragma unroll
    for (int s = 0; s < 2; ++s)
        if ((srm >> s) & 1u) u_r[s] += minv - srv_r[s];
#pragma unroll
    for (int s = 0; s < NSLOT; ++s)
        if ((sc >> s) & 1u) v[s] -= (minv - sh[s]);
    // augment (wave-cooperative, uniform walk)
    int j = sink;
    while (true) {
        int plane = COL_OWNER_LANE(j);
        int pslot = COL_SLOT(j);
        int pv = 0;
#pragma unroll
        for (int s = 0; s < NSLOT; ++s)
            if (s == pslot) pv = path_r[s];
        int pi = __builtin_amdgcn_readlane(pv, plane);
        if (lane == plane) {
#pragma unroll
            for (int s = 0; s < NSLOT; ++s)
                if (s == pslot) r4c_r[s] = pi;
        }
        int cslot = pi >> 6, clane = pi & 63;
        int cvv = 0;
#pragma unroll
        for (int s = 0; s < 2; ++s)
            if (s == cslot) cvv = c4r_r[s];
        int nj = __builtin_amdgcn_readlane(cvv, clane);
        if (lane == clane) {
#pragma unroll
            for (int s = 0; s < 2; ++s)
                if (s == cslot) c4r_r[s] = j;
        }
        j = nj;
        if (pi == cur) break;
    }
    return true;
}

// R10-proven exact LSA: v=0 init, sequential SAP rows 0..n-1 (scipy traversal).
// One 64-lane wave per batch, all state in registers. + 2-deep alternating
// prefetch (pfA/pfB) + lean-scan u64 reduce + float4 column remap.
__global__ __launch_bounds__(64, 1) void lsa_kernel(const float* __restrict__ cost,
                                                    const int* __restrict__ nvalid,
                                                    const int* __restrict__ valid_idx,
                                                    const int* __restrict__ glabels,
                                                    const float* __restrict__ lse_g,
                                                    const float* __restrict__ pboxes,
                                                    const float* __restrict__ gboxes,
                                                    const float* __restrict__ logits,
                                                    double* __restrict__ mpart) {
    int b = blockIdx.x;
    int n = nvalid[b];
    const float* cbase = cost + (size_t)b * GG * QQ;
    int lane = threadIdx.x;

    float v[NSLOT];
    int r4c_r[NSLOT];
    float u_r[2];
    int c4r_r[2];
    float pfA[NSLOT], pfB[NSLOT];
    // groups 0..2 valid for all lanes (cols 0..767); group 3 valid lanes<=32
    unsigned valid_mask = 0x0FFFu | ((lane <= 32) ? 0xF000u : 0u);
#pragma unroll
    for (int s = 0; s < NSLOT; ++s) { v[s] = 0.f; r4c_r[s] = -1; pfA[s] = 0.f; pfB[s] = 0.f; }
#pragma unroll
    for (int s = 0; s < 2; ++s) { u_r[s] = 0.f; c4r_r[s] = -1; }

    if (n > 0) load_row_f4(cbase, lane, pfA);           // prime pfA with row 0
    if (n > 1) load_row_f4(cbase + QQ, lane, pfB);      // prime pfB with row 1
    {
        int cur = 0;
        for (; cur + 1 < n; cur += 2) {
            sap_phase(cur, lane, cbase, valid_mask, v, r4c_r, u_r, c4r_r, pfA, n);
            sap_phase(cur + 1, lane, cbase, valid_mask, v, r4c_r, u_r, c4r_r, pfB, n);
        }
        if (cur < n)
            sap_phase(cur, lane, cbase, valid_mask, v, r4c_r, u_r, c4r_r, pfA, n);
    }

    // ---- fused matched-pair losses ----
    double ce = 0.0, dl1 = 0.0, dgi = 0.0;
#pragma unroll
    for (int s = 0; s < 2; ++s) {
        int r = s * 64 + lane;
        int q = c4r_r[s];
        if (r < n && q >= 0 && q < QQ) {
            int g = valid_idx[b * GG + r];
            int label = glabels[b * GG + g];
            if (label < 0 || label >= CC) label = 0;
            size_t ro = ((size_t)b * QQ + q) * CC;
            float ls = lse_g[b * QQ + q];
            float nll_lab = ls - logits[ro + label];
            float nll_no = ls - logits[ro + NCL];
            ce += 0.1 * (double)nll_lab - (double)nll_no;
            float4 pb = ((const float4*)pboxes)[b * QQ + q];
            float4 gb = ((const float4*)gboxes)[b * GG + g];
            float l1 = fabsf(pb.x - gb.x) + fabsf(pb.y - gb.y) + fabsf(pb.z - gb.z) + fabsf(pb.w - gb.w);
            float px0 = pb.x - 0.5f * pb.z, py0 = pb.y - 0.5f * pb.w;
            float px1 = pb.x + 0.5f * pb.z, py1 = pb.y + 0.5f * pb.w;
            float gx0 = gb.x - 0.5f * gb.z, gy0 = gb.y - 0.5f * gb.w;
            float gx1 = gb.x + 0.5f * gb.z, gy1 = gb.y + 0.5f * gb.w;
            float parea = (px1 - px0) * (py1 - py0);
            float garea = (gx1 - gx0) * (gy1 - gy0);
            float ltx = fmaxf(px0, gx0), lty = fmaxf(py0, gy0);
            float rbx = fminf(px1, gx1), rby = fminf(py1, gy1);
            float iw = fmaxf(rbx - ltx, 0.f), ih = fmaxf(rby - lty, 0.f);
            float inter = iw * ih;
            float uni = parea + garea - inter;
            float iou = inter / uni;
            float cx0 = fminf(px0, gx0), cy0 = fminf(py0, gy0);
            float cx1 = fmaxf(px1, gx1), cy1 = fmaxf(py1, gy1);
            float cw = fmaxf(cx1 - cx0, 0.f), ch = fmaxf(cy1 - cy0, 0.f);
            float ac = cw * ch;
            float giou = iou - (ac - uni) / ac;
            dl1 += (double)l1;
            dgi += 1.0 - (double)giou;
        }
    }
#pragma unroll
    for (int off = 32; off; off >>= 1) {
        ce += __shfl_down(ce, off);
        dl1 += __shfl_down(dl1, off);
        dgi += __shfl_down(dgi, off);
    }
    if (lane == 0) {
        mpart[b * 3 + 0] = ce;
        mpart[b * 3 + 1] = dl1;
        mpart[b * 3 + 2] = dgi;
    }
}

// One wave: sum partials + nvalid -> the three losses (no atomics anywhere).
__global__ __launch_bounds__(64) void final_kernel(const int* __restrict__ nvalid,
                                                   const float* __restrict__ fpart,
                                                   const double* __restrict__ mpart,
                                                   float* __restrict__ out) {
    int lane = threadIdx.x;
    int m = nvalid[lane] + nvalid[64 + lane];  // BB = 128
    double fb = 0.0;
    for (int i = lane; i < BB * NPART; i += 64) fb += (double)fpart[i];
    double ce = 0.0, dl1 = 0.0, dgi = 0.0;
#pragma unroll
    for (int s = 0; s < 2; ++s) {
        int bb = s * 64 + lane;
        ce += mpart[bb * 3 + 0];
        dl1 += mpart[bb * 3 + 1];
        dgi += mpart[bb * 3 + 2];
    }
#pragma unroll
    for (int off = 32; off; off >>= 1) {
        m += __shfl_down(m, off);
        fb += __shfl_down(fb, off);
        ce += __shfl_down(ce, off);
        dl1 += __shfl_down(dl1, off);
        dgi += __shfl_down(dgi, off);
    }
    if (lane == 0) {
        double M = (double)m;
        double sum_w = (double)(BB * QQ) - 0.9 * M;
        out[0] = (float)((fb + ce) / sum_w);
        out[1] = (float)(dl1 / (4.0 * M));
        out[2] = (float)(dgi / M);
    }
}

extern "C" void kernel_launch(void* const* d_in, const int* in_sizes, int n_in,
                              void* d_out, int out_size, void* d_ws, size_t ws_size,
                              hipStream_t stream) {
    const float* logits = (const float*)d_in[0];
    const float* pboxes = (const float*)d_in[1];
    const int* glabels = (const int*)d_in[2];
    const float* gboxes = (const float*)d_in[3];
    float* out = (float*)d_out;

    char* ws = (char*)d_ws;
    float* cost = (float*)(ws + COST_OFF);
    float* lse = (float*)(ws + LSE_OFF);
    int* vidx = (int*)(ws + VIDX_OFF);
    int* nval = (int*)(ws + NV_OFF);
    float* fpart = (float*)(ws + FPART_OFF);
    double* mpart = (double*)(ws + MPART_OFF);

    (void)hipFuncSetAttribute((const void*)front_kernel,
                              hipFuncAttributeMaxDynamicSharedMemorySize, FRONT_LDS_BYTES);

    front_kernel<<<BB * NPART, 128, FRONT_LDS_BYTES, stream>>>(logits, pboxes, gboxes, glabels,
                                                               lse, vidx, nval, cost, fpart);
    lsa_kernel<<<BB, 64, 0, stream>>>(cost, nval, vidx, glabels, lse, pboxes, gboxes, logits, mpart);
    final_kernel<<<1, 64, 0, stream>>>(nval, fpart, mpart, out);
}